// Round 8
// baseline (212.967 us; speedup 1.0000x reference)
//
#include <hip/hip_runtime.h>

typedef __bf16 bf16x8 __attribute__((ext_vector_type(8)));
typedef float f32x4 __attribute__((ext_vector_type(4)));
typedef short short4v __attribute__((ext_vector_type(4)));
typedef short short8v __attribute__((ext_vector_type(8)));

#define DEVI static __device__ __forceinline__

// fp32 -> bf16 bits via hardware cvt (RTNE; pairs fold to v_cvt_pk_bf16_f32)
DEVI short f2bf(float f) {
    union { __bf16 b; short s; } u;
    u.b = (__bf16)f;
    return u.s;
}

// async global -> LDS, 16B per lane (dest linear: wave-uniform base + lane*16)
DEVI void gld16(const void* g, void* l) {
    __builtin_amdgcn_global_load_lds(
        (const __attribute__((address_space(1))) unsigned int*)g,
        (__attribute__((address_space(3))) unsigned int*)l, 16, 0, 0);
}

// ---------------- x fp32 -> bf16 ----------------
__global__ __launch_bounds__(256) void cvt_x_kernel(const float* __restrict__ x,
                                                    short* __restrict__ xb) {
    int i = (blockIdx.x * 256 + threadIdx.x) * 8;
    f32x4 a = *(const f32x4*)(x + i);
    f32x4 b = *(const f32x4*)(x + i + 4);
    short8v o;
    o[0]=f2bf(a[0]); o[1]=f2bf(a[1]); o[2]=f2bf(a[2]); o[3]=f2bf(a[3]);
    o[4]=f2bf(b[0]); o[5]=f2bf(b[1]); o[6]=f2bf(b[2]); o[7]=f2bf(b[3]);
    *(short8v*)(xb + i) = o;
}

// ------------- 5x weight [K=1024][N=1024] fp32 -> [N][K] bf16 (transpose), fused -------------
__global__ __launch_bounds__(256) void wtrans5_kernel(const float* __restrict__ w0,
                                                      const float* __restrict__ w1,
                                                      const float* __restrict__ w2,
                                                      const float* __restrict__ w3,
                                                      const float* __restrict__ w4,
                                                      short* __restrict__ dst) {
    const float* w;
    switch (blockIdx.z) {
        case 0: w = w0; break;
        case 1: w = w1; break;
        case 2: w = w2; break;
        case 3: w = w3; break;
        default: w = w4; break;
    }
    short* wt = dst + (size_t)blockIdx.z * 1048576;
    __shared__ float t[64][68];
    const int tid = threadIdx.x;
    const int k0 = blockIdx.x * 64, n0 = blockIdx.y * 64;
#pragma unroll
    for (int it = 0; it < 4; ++it) {
        int r = (tid >> 4) + it * 16;
        int cc = (tid & 15) * 4;
        f32x4 vv = *(const f32x4*)(w + (k0 + r) * 1024 + n0 + cc);
        *(f32x4*)&t[r][cc] = vv;
    }
    __syncthreads();
#pragma unroll
    for (int it = 0; it < 4; ++it) {
        int n = (tid >> 4) + it * 16;
        int kc = (tid & 15) * 4;
        short4v o;
        o[0] = f2bf(t[kc + 0][n]);
        o[1] = f2bf(t[kc + 1][n]);
        o[2] = f2bf(t[kc + 2][n]);
        o[3] = f2bf(t[kc + 3][n]);
        *(short4v*)(wt + (n0 + n) * 1024 + k0 + kc) = o;
    }
}

// ---------------- GEMM v4: C[M,N] = A[M,1024] @ Bt[N,1024]^T ----------------
// 256x128 tile, 512 threads / 8 waves (4M x 2N, per-wave 64x64), BK=64.
// 3-slot LDS ring (144 KB), counted vmcnt(6), PHASE-LOCKED schedule (T3):
// per K-tile: vmcnt(6) -> BAR -> ISSUE(kt+2) ->
//   {readsA -> BAR -> lgkm0 -> setprio 16xMFMA} -> {readsB -> BAR -> lgkm0 -> setprio 16xMFMA}
// Small MFMA clusters between barriers keep all 8 waves phase-locked so per-phase
// overhead (~100cy) amortizes vs 154cy MFMA window (m201 mechanism). Ledger:
// slot is=(kt+2)%3 last read iter kt-1, fenced by top BAR; vmcnt(6) retires tile
// kt's 6 loads (in-order), tile kt+1's stay in flight; cross-wave staging
// visibility = per-wave vmcnt(6) before top BAR. Tail peels kt=14 (vmcnt6, no
// issue) and kt=15 (vmcnt0). T2 swizzle: linear LDS dest, global SOURCE column
// pre-XOR'd (involution), reads apply same XOR (rule 21).
// MODE 0: scatter bf16 to q/k/v [which][b*16+h][t][64]   (outp = qkv base)
// MODE 1: bf16 out = acc + bias
// MODE 2: fp32 out = relu(acc + bias)
template<int MODE>
__global__ __launch_bounds__(512, 2) void gemm_bt(const short* __restrict__ A,
                                                  const short* __restrict__ Bt,
                                                  const float* __restrict__ bias,
                                                  void* __restrict__ outp) {
    __shared__ short As[3][256 * 64];  // 96 KB
    __shared__ short Bs[3][128 * 64];  // 48 KB
    const int tid = threadIdx.x;
    const int lane = tid & 63;
    const int wid = tid >> 6;          // 0..7
    const int g = lane >> 4, c = lane & 15;
    const int wr = wid >> 1, wc = wid & 1;   // 4M x 2N wave grid
    const int m0 = blockIdx.x * 256, n0 = blockIdx.y * 128;

    const f32x4 fz = {0.f, 0.f, 0.f, 0.f};
    f32x4 acc[4][4];
#pragma unroll
    for (int m = 0; m < 4; ++m)
#pragma unroll
        for (int n = 0; n < 4; ++n) acc[m][n] = fz;

    // staging: A = 4 chunks/thread, B = 2 chunks/thread, 16B each (6 gld16/thread/K-tile)
    auto ISSUE = [&](int kt, int slot) {
        const int k0 = kt * 64;
#pragma unroll
        for (int j = 0; j < 4; ++j) {
            int ci = j * 512 + tid;
            int r = ci >> 3, cc = ((ci & 7) ^ (r & 7)) << 3;  // pre-swizzled source
            gld16(A + (m0 + r) * 1024 + k0 + cc, (char*)&As[slot][0] + ci * 16);
        }
#pragma unroll
        for (int j = 0; j < 2; ++j) {
            int ci = j * 512 + tid;
            int r = ci >> 3, cc = ((ci & 7) ^ (r & 7)) << 3;
            gld16(Bt + (n0 + r) * 1024 + k0 + cc, (char*)&Bs[slot][0] + ci * 16);
        }
    };

    // one phase: read frags for (slot,kk), barrier-lock, wait, MFMA cluster
    auto PHASE = [&](int slot, int kk) {
        const char* ab = (const char*)&As[slot][0];
        const char* bb = (const char*)&Bs[slot][0];
        bf16x8 af[4], bfr[4];
#pragma unroll
        for (int m = 0; m < 4; ++m) {
            int row = wr * 64 + m * 16 + c;
            af[m] = *(const bf16x8*)(ab + row * 128 + ((kk * 64 + g * 16) ^ ((row & 7) << 4)));
        }
#pragma unroll
        for (int n = 0; n < 4; ++n) {
            int row = wc * 64 + n * 16 + c;
            bfr[n] = *(const bf16x8*)(bb + row * 128 + ((kk * 64 + g * 16) ^ ((row & 7) << 4)));
        }
        __builtin_amdgcn_sched_barrier(0);
        __builtin_amdgcn_s_barrier();
        asm volatile("s_waitcnt lgkmcnt(0)" ::: "memory");
        __builtin_amdgcn_sched_barrier(0);
        __builtin_amdgcn_s_setprio(1);
#pragma unroll
        for (int m = 0; m < 4; ++m)
#pragma unroll
            for (int n = 0; n < 4; ++n)
                acc[m][n] = __builtin_amdgcn_mfma_f32_16x16x32_bf16(af[m], bfr[n], acc[m][n], 0, 0, 0);
        __builtin_amdgcn_s_setprio(0);
        __builtin_amdgcn_sched_barrier(0);
    };

    ISSUE(0, 0);
    ISSUE(1, 1);
    int cs = 0, is = 2;  // compute slot, issue slot
#pragma unroll 1
    for (int kt = 0; kt < 14; ++kt) {
        asm volatile("s_waitcnt vmcnt(6)" ::: "memory");
        __builtin_amdgcn_sched_barrier(0);
        __builtin_amdgcn_s_barrier();
        __builtin_amdgcn_sched_barrier(0);
        ISSUE(kt + 2, is);
        PHASE(cs, 0);
        PHASE(cs, 1);
        cs = (cs == 2) ? 0 : cs + 1;
        is = (is == 2) ? 0 : is + 1;
    }
    // kt = 14: tile 14 landed, tile 15's 6 loads stay in flight
    asm volatile("s_waitcnt vmcnt(6)" ::: "memory");
    __builtin_amdgcn_sched_barrier(0);
    __builtin_amdgcn_s_barrier();
    __builtin_amdgcn_sched_barrier(0);
    PHASE(cs, 0);
    PHASE(cs, 1);
    cs = (cs == 2) ? 0 : cs + 1;
    // kt = 15: drain
    asm volatile("s_waitcnt vmcnt(0)" ::: "memory");
    __builtin_amdgcn_sched_barrier(0);
    __builtin_amdgcn_s_barrier();
    __builtin_amdgcn_sched_barrier(0);
    PHASE(cs, 0);
    PHASE(cs, 1);

#pragma unroll
    for (int n = 0; n < 4; ++n) {
        const int col = n0 + wc * 64 + n * 16 + c;
        float bv = 0.f;
        if (MODE != 0) bv = bias[col];
#pragma unroll
        for (int m = 0; m < 4; ++m) {
            const int row0 = m0 + wr * 64 + m * 16 + g * 4;
#pragma unroll
            for (int i = 0; i < 4; ++i) {
                const int row = row0 + i;
                float val = acc[m][n][i];
                if (MODE == 0) {
                    short* qkv = (short*)outp;
                    int which = col >> 10;
                    int hc = col & 1023;
                    int dst = which * 8388608 +
                              (((row >> 10) * 16 + (hc >> 6)) * 1024 + (row & 1023)) * 64 + (hc & 63);
                    qkv[dst] = f2bf(val);
                } else if (MODE == 1) {
                    ((short*)outp)[row * 1024 + col] = f2bf(val + bv);
                } else {
                    ((float*)outp)[row * 1024 + col] = fmaxf(val + bv, 0.f);
                }
            }
        }
    }
}

// ---------------- causal flash attention v3.1 (unchanged, passing) ----------------
__global__ __launch_bounds__(512, 2) void attn_kernel(const short* __restrict__ qp,
                                                      const short* __restrict__ kp,
                                                      const short* __restrict__ vp,
                                                      short* __restrict__ ao) {
    __shared__ short Ks[128 * 64];     // row t: 128B rows, swz ((r&7)<<4)
    __shared__ short Vt[64 * 128];     // row d: 256B rows, swz (((d&7)^(d>>3))<<4)
    __shared__ short Ps[8][16 * 128];  // per-wave, row q: 256B rows, swz ((q&7)<<4)
    const float SCALE = 0.125f * 1.44269504088896340736f;  // 1/sqrt(64) * log2(e)
    const int tid = threadIdx.x;
    const int lane = tid & 63;
    const int wid = tid >> 6;
    const int g = lane >> 4, c = lane & 15;
    const int bh = blockIdx.y;
    const int base = bh * 65536;  // 1024*64
    const int b = bh >> 4, h = bh & 15;

    const int r0 = tid >> 3, c0 = (tid & 7) << 3;
    const int r1 = 64 + r0;
    const int vt0 = (tid >> 4) * 4;   // 0..124
    const int vd0 = (tid & 15) * 4;   // 0..60

    const f32x4 fz = {0.f, 0.f, 0.f, 0.f};

    bf16x8 kreg0, kreg1;
    short4v vreg0, vreg1, vreg2, vreg3;

#pragma unroll 1
    for (int ph = 0; ph < 2; ++ph) {
        const int qt = ph ? (7 - blockIdx.x) : blockIdx.x;
        const int q0 = qt * 128;
        const int nkt = qt + 1;

        const int qrow = q0 + wid * 16 + c;
        bf16x8 qf0 = *(const bf16x8*)(qp + base + qrow * 64 + g * 8);
        bf16x8 qf1 = *(const bf16x8*)(qp + base + qrow * 64 + 32 + g * 8);

        f32x4 accO[4];
#pragma unroll
        for (int n = 0; n < 4; ++n) accO[n] = fz;
        float mrow[4], lrow[4];
#pragma unroll
        for (int i = 0; i < 4; ++i) { mrow[i] = -1e30f; lrow[i] = 0.f; }

        kreg0 = *(const bf16x8*)(kp + base + r0 * 64 + c0);
        kreg1 = *(const bf16x8*)(kp + base + r1 * 64 + c0);
        vreg0 = *(const short4v*)(vp + base + (vt0 + 0) * 64 + vd0);
        vreg1 = *(const short4v*)(vp + base + (vt0 + 1) * 64 + vd0);
        vreg2 = *(const short4v*)(vp + base + (vt0 + 2) * 64 + vd0);
        vreg3 = *(const short4v*)(vp + base + (vt0 + 3) * 64 + vd0);

        for (int kt = 0; kt < nkt; ++kt) {
            __syncthreads();
            *(bf16x8*)((char*)Ks + r0 * 128 + ((c0 * 2) ^ ((r0 & 7) << 4))) = kreg0;
            *(bf16x8*)((char*)Ks + r1 * 128 + ((c0 * 2) ^ ((r1 & 7) << 4))) = kreg1;
#pragma unroll
            for (int i = 0; i < 4; ++i) {
                short4v w; w[0] = vreg0[i]; w[1] = vreg1[i]; w[2] = vreg2[i]; w[3] = vreg3[i];
                int d = vd0 + i;
                int swz = ((d & 7) ^ (d >> 3)) << 4;
                *(short4v*)((char*)Vt + d * 256 + ((vt0 * 2) ^ swz)) = w;
            }
            if (kt + 1 < nkt) {
                const short* kp2 = kp + base + (kt + 1) * 8192;
                const short* vp2 = vp + base + (kt + 1) * 8192;
                kreg0 = *(const bf16x8*)(kp2 + r0 * 64 + c0);
                kreg1 = *(const bf16x8*)(kp2 + r1 * 64 + c0);
                vreg0 = *(const short4v*)(vp2 + (vt0 + 0) * 64 + vd0);
                vreg1 = *(const short4v*)(vp2 + (vt0 + 1) * 64 + vd0);
                vreg2 = *(const short4v*)(vp2 + (vt0 + 2) * 64 + vd0);
                vreg3 = *(const short4v*)(vp2 + (vt0 + 3) * 64 + vd0);
            }
            __syncthreads();

            const bool diag = (kt == nkt - 1);
            const int nlim = diag ? (wid + 1) : 8;

            f32x4 s[8];
#pragma unroll
            for (int n = 0; n < 8; ++n) {
                s[n] = fz;
                if (n < nlim) {
                    int row = n * 16 + c;
                    int swz = (row & 7) << 4;
                    bf16x8 kf0 = *(const bf16x8*)((const char*)Ks + row * 128 + ((g * 16) ^ swz));
                    bf16x8 kf1 = *(const bf16x8*)((const char*)Ks + row * 128 + ((64 + g * 16) ^ swz));
                    s[n] = __builtin_amdgcn_mfma_f32_16x16x32_bf16(qf0, kf0, s[n], 0, 0, 0);
                    s[n] = __builtin_amdgcn_mfma_f32_16x16x32_bf16(qf1, kf1, s[n], 0, 0, 0);
                }
            }

            const int qg0 = q0 + wid * 16 + g * 4;
            float pm[4];
#pragma unroll
            for (int i = 0; i < 4; ++i) pm[i] = -1e30f;
            if (diag) {
#pragma unroll
                for (int n = 0; n < 8; ++n) {
                    int kg = kt * 128 + n * 16 + c;
#pragma unroll
                    for (int i = 0; i < 4; ++i) {
                        float vv = s[n][i] * SCALE;
                        vv = (kg <= qg0 + i) ? vv : -1e30f;
                        s[n][i] = vv;
                        pm[i] = fmaxf(pm[i], vv);
                    }
                }
            } else {
#pragma unroll
                for (int n = 0; n < 8; ++n)
#pragma unroll
                    for (int i = 0; i < 4; ++i) {
                        float vv = s[n][i] * SCALE;
                        s[n][i] = vv;
                        pm[i] = fmaxf(pm[i], vv);
                    }
            }
#pragma unroll
            for (int off = 1; off < 16; off <<= 1)
#pragma unroll
                for (int i = 0; i < 4; ++i)
                    pm[i] = fmaxf(pm[i], __shfl_xor(pm[i], off));

            int need = 0;
#pragma unroll
            for (int i = 0; i < 4; ++i) need |= (pm[i] > mrow[i] + 8.f) ? 1 : 0;
            if (__any(need)) {
#pragma unroll
                for (int i = 0; i < 4; ++i) {
                    float mnew = fmaxf(mrow[i], pm[i]);
                    float corr = exp2f(mrow[i] - mnew);
                    mrow[i] = mnew;
                    lrow[i] *= corr;
#pragma unroll
                    for (int n = 0; n < 4; ++n) accO[n][i] *= corr;
                }
            }
            float rs[4];
#pragma unroll
            for (int i = 0; i < 4; ++i) rs[i] = 0.f;
#pragma unroll
            for (int n = 0; n < 8; ++n)
#pragma unroll
                for (int i = 0; i < 4; ++i) {
                    float pv = exp2f(s[n][i] - mrow[i]);
                    s[n][i] = pv;
                    rs[i] += pv;
                }
#pragma unroll
            for (int off = 1; off < 16; off <<= 1)
#pragma unroll
                for (int i = 0; i < 4; ++i)
                    rs[i] += __shfl_xor(rs[i], off);
#pragma unroll
            for (int i = 0; i < 4; ++i) lrow[i] += rs[i];

#pragma unroll
            for (int n = 0; n < 8; ++n) {
                int t = n * 16 + c;
#pragma unroll
                for (int i = 0; i < 4; ++i) {
                    int q = g * 4 + i;
                    *(short*)((char*)&Ps[wid][0] + q * 256 + ((t * 2) ^ ((q & 7) << 4))) = f2bf(s[n][i]);
                }
            }

#pragma unroll
            for (int ks = 0; ks < 4; ++ks) {
                bf16x8 paf = *(const bf16x8*)((const char*)&Ps[wid][0] +
                                              c * 256 + ((ks * 64 + g * 16) ^ ((c & 7) << 4)));
#pragma unroll
                for (int n = 0; n < 4; ++n) {
                    int d = n * 16 + c;
                    int swz = ((d & 7) ^ (d >> 3)) << 4;
                    bf16x8 vf = *(const bf16x8*)((const char*)Vt + d * 256 + ((ks * 64 + g * 16) ^ swz));
                    accO[n] = __builtin_amdgcn_mfma_f32_16x16x32_bf16(paf, vf, accO[n], 0, 0, 0);
                }
            }
        }

        float inv[4];
#pragma unroll
        for (int i = 0; i < 4; ++i) inv[i] = __builtin_amdgcn_rcpf(lrow[i]);
#pragma unroll
        for (int n = 0; n < 4; ++n)
#pragma unroll
            for (int i = 0; i < 4; ++i) {
                int t = q0 + wid * 16 + g * 4 + i;
                float o = accO[n][i] * inv[i];
                ao[(b * 1024 + t) * 1024 + h * 64 + n * 16 + c] = f2bf(o);
            }
    }
}

extern "C" void kernel_launch(void* const* d_in, const int* in_sizes, int n_in,
                              void* d_out, int out_size, void* d_ws, size_t ws_size,
                              hipStream_t stream) {
    const float* x  = (const float*)d_in[0];
    const float* Wq = (const float*)d_in[1];
    const float* Wk = (const float*)d_in[2];
    const float* Wv = (const float*)d_in[3];
    const float* Wo = (const float*)d_in[4];
    const float* bo = (const float*)d_in[5];
    const float* W1 = (const float*)d_in[6];
    const float* b1 = (const float*)d_in[7];

    char* ws = (char*)d_ws;
    short* xb    = (short*)(ws + 0);          // 16.78 MB  [8192][1024] bf16
    short* wallT = (short*)(ws + 16777216);   // 10.49 MB  5x [1024][1024] bf16 (Wq,Wk,Wv,Wo,W1)^T
    short* qb    = (short*)(ws + 27262976);   // 3 x 16.78 MB: q,k,v [B*H][T][64] bf16
    short* kb    = qb + 8388608;
    short* vb    = qb + 16777216;
    short* ao    = xb;                        // reuse: attention out [8192][1024] bf16
    short* o2    = qb;                        // reuse: Wo out [8192][1024] bf16
    short* wqkvT = wallT;                     // Wq^T|Wk^T|Wv^T contiguous
    short* woT   = wallT + 3145728;
    short* w1T   = wallT + 4194304;

    cvt_x_kernel<<<4096, 256, 0, stream>>>(x, xb);
    wtrans5_kernel<<<dim3(16, 16, 5), 256, 0, stream>>>(Wq, Wk, Wv, Wo, W1, wallT);

    gemm_bt<0><<<dim3(32, 24), 512, 0, stream>>>(xb, wqkvT, nullptr, (void*)qb);
    attn_kernel<<<dim3(4, 128), 512, 0, stream>>>(qb, kb, vb, ao);
    gemm_bt<1><<<dim3(32, 8), 512, 0, stream>>>(ao, woT, bo, (void*)o2);
    gemm_bt<2><<<dim3(32, 8), 512, 0, stream>>>(o2, w1T, b1, d_out);
}

// Round 9
// 173.826 us; speedup vs baseline: 1.2252x; 1.2252x over previous
//
#include <hip/hip_runtime.h>

typedef __bf16 bf16x8 __attribute__((ext_vector_type(8)));
typedef float f32x4 __attribute__((ext_vector_type(4)));
typedef short short4v __attribute__((ext_vector_type(4)));
typedef short short8v __attribute__((ext_vector_type(8)));

#define DEVI static __device__ __forceinline__

// fp32 -> bf16 bits via hardware cvt (RTNE; pairs fold to v_cvt_pk_bf16_f32)
DEVI short f2bf(float f) {
    union { __bf16 b; short s; } u;
    u.b = (__bf16)f;
    return u.s;
}

// async global -> LDS, 16B per lane (dest linear: wave-uniform base + lane*16)
DEVI void gld16(const void* g, void* l) {
    __builtin_amdgcn_global_load_lds(
        (const __attribute__((address_space(1))) unsigned int*)g,
        (__attribute__((address_space(3))) unsigned int*)l, 16, 0, 0);
}

// ---------------- x fp32 -> bf16 ----------------
__global__ __launch_bounds__(256) void cvt_x_kernel(const float* __restrict__ x,
                                                    short* __restrict__ xb) {
    int i = (blockIdx.x * 256 + threadIdx.x) * 8;
    f32x4 a = *(const f32x4*)(x + i);
    f32x4 b = *(const f32x4*)(x + i + 4);
    short8v o;
    o[0]=f2bf(a[0]); o[1]=f2bf(a[1]); o[2]=f2bf(a[2]); o[3]=f2bf(a[3]);
    o[4]=f2bf(b[0]); o[5]=f2bf(b[1]); o[6]=f2bf(b[2]); o[7]=f2bf(b[3]);
    *(short8v*)(xb + i) = o;
}

// ------------- 5x weight [K=1024][N=1024] fp32 -> [N][K] bf16 (transpose), fused -------------
__global__ __launch_bounds__(256) void wtrans5_kernel(const float* __restrict__ w0,
                                                      const float* __restrict__ w1,
                                                      const float* __restrict__ w2,
                                                      const float* __restrict__ w3,
                                                      const float* __restrict__ w4,
                                                      short* __restrict__ dst) {
    const float* w;
    switch (blockIdx.z) {
        case 0: w = w0; break;
        case 1: w = w1; break;
        case 2: w = w2; break;
        case 3: w = w3; break;
        default: w = w4; break;
    }
    short* wt = dst + (size_t)blockIdx.z * 1048576;
    __shared__ float t[64][68];
    const int tid = threadIdx.x;
    const int k0 = blockIdx.x * 64, n0 = blockIdx.y * 64;
#pragma unroll
    for (int it = 0; it < 4; ++it) {
        int r = (tid >> 4) + it * 16;
        int cc = (tid & 15) * 4;
        f32x4 vv = *(const f32x4*)(w + (k0 + r) * 1024 + n0 + cc);
        *(f32x4*)&t[r][cc] = vv;
    }
    __syncthreads();
#pragma unroll
    for (int it = 0; it < 4; ++it) {
        int n = (tid >> 4) + it * 16;
        int kc = (tid & 15) * 4;
        short4v o;
        o[0] = f2bf(t[kc + 0][n]);
        o[1] = f2bf(t[kc + 1][n]);
        o[2] = f2bf(t[kc + 2][n]);
        o[3] = f2bf(t[kc + 3][n]);
        *(short4v*)(wt + (n0 + n) * 1024 + k0 + kc) = o;
    }
}

// ---------------- GEMM (round-5 m97 structure + T2 swizzle): C = A @ Bt^T ----------------
// 128x128 tile, 256 threads / 4 waves (2x2), BK=64, single LDS buffer 32KB,
// __syncthreads (compiler drain) -- latency hidden by 2 blocks/CU cross-overlap (m114).
// T2: gld16 dest linear, global SOURCE column pre-XOR'd (involution), reads same XOR.
// MODE 0: scatter bf16 to q/k/v [which][b*16+h][t][64]   (outp = qkv base)
// MODE 1: bf16 out = acc + bias
// MODE 2: fp32 out = relu(acc + bias)
template<int MODE>
__global__ __launch_bounds__(256, 2) void gemm_bt(const short* __restrict__ A,
                                                  const short* __restrict__ Bt,
                                                  const float* __restrict__ bias,
                                                  void* __restrict__ outp) {
    __shared__ short As[128 * 64];
    __shared__ short Bs[128 * 64];
    const int tid = threadIdx.x;
    const int lane = tid & 63;
    const int wid = tid >> 6;
    const int g = lane >> 4, c = lane & 15;
    const int wr = wid >> 1, wc = wid & 1;
    const int m0 = blockIdx.x * 128, n0 = blockIdx.y * 128;

    const f32x4 fz = {0.f, 0.f, 0.f, 0.f};
    f32x4 acc[4][4];
#pragma unroll
    for (int m = 0; m < 4; ++m)
#pragma unroll
        for (int n = 0; n < 4; ++n) acc[m][n] = fz;

    for (int kt = 0; kt < 16; ++kt) {
        const int k0 = kt * 64;
        __syncthreads();
#pragma unroll
        for (int st = 0; st < 4; ++st) {
            int ci = st * 256 + tid;
            int r = ci >> 3;
            int cc = ((ci & 7) ^ (r & 7)) << 3;   // pre-swizzled source (involution)
            gld16(A + (m0 + r) * 1024 + k0 + cc, (char*)As + ci * 16);
            gld16(Bt + (n0 + r) * 1024 + k0 + cc, (char*)Bs + ci * 16);
        }
        __syncthreads();
#pragma unroll
        for (int kk = 0; kk < 2; ++kk) {
            bf16x8 af[4], bfr[4];
#pragma unroll
            for (int m = 0; m < 4; ++m) {
                int row = wr * 64 + m * 16 + c;
                af[m] = *(const bf16x8*)((const char*)As + row * 128 + ((kk * 64 + g * 16) ^ ((row & 7) << 4)));
            }
#pragma unroll
            for (int n = 0; n < 4; ++n) {
                int row = wc * 64 + n * 16 + c;
                bfr[n] = *(const bf16x8*)((const char*)Bs + row * 128 + ((kk * 64 + g * 16) ^ ((row & 7) << 4)));
            }
#pragma unroll
            for (int m = 0; m < 4; ++m)
#pragma unroll
                for (int n = 0; n < 4; ++n)
                    acc[m][n] = __builtin_amdgcn_mfma_f32_16x16x32_bf16(af[m], bfr[n], acc[m][n], 0, 0, 0);
        }
    }

#pragma unroll
    for (int n = 0; n < 4; ++n) {
        const int col = n0 + wc * 64 + n * 16 + c;
        float bv = 0.f;
        if (MODE != 0) bv = bias[col];
#pragma unroll
        for (int m = 0; m < 4; ++m) {
            const int row0 = m0 + wr * 64 + m * 16 + g * 4;
#pragma unroll
            for (int i = 0; i < 4; ++i) {
                const int row = row0 + i;
                float val = acc[m][n][i];
                if (MODE == 0) {
                    short* qkv = (short*)outp;
                    int which = col >> 10;
                    int hc = col & 1023;
                    int dst = which * 8388608 +
                              (((row >> 10) * 16 + (hc >> 6)) * 1024 + (row & 1023)) * 64 + (hc & 63);
                    qkv[dst] = f2bf(val);
                } else if (MODE == 1) {
                    ((short*)outp)[row * 1024 + col] = f2bf(val + bv);
                } else {
                    ((float*)outp)[row * 1024 + col] = fmaxf(val + bv, 0.f);
                }
            }
        }
    }
}

// ---------------- causal flash attention v3.2 ----------------
// grid (4, B*H), 512 threads / 8 waves; q-tile pairing {bx, 7-bx} (9 tiles/block).
// K/V reg-prefetch (T14); diag-only masking; defer-max (T13); setprio on MFMA (T5);
// per-lane deferred row-sum (reduce once in epilogue); Ps split into 64-key halves
// -> LDS 48KB (3 blocks/CU capacity).
__global__ __launch_bounds__(512, 2) void attn_kernel(const short* __restrict__ qp,
                                                      const short* __restrict__ kp,
                                                      const short* __restrict__ vp,
                                                      short* __restrict__ ao) {
    __shared__ short Ks[128 * 64];    // row t: 128B rows, swz ((r&7)<<4)
    __shared__ short Vt[64 * 128];    // row d: 256B rows, swz (((d&7)^(d>>3))<<4)
    __shared__ short Ps[8][16 * 64];  // per-wave P half [q][64], 128B rows, swz ((q&7)<<4)
    const float SCALE = 0.125f * 1.44269504088896340736f;  // 1/sqrt(64) * log2(e)
    const int tid = threadIdx.x;
    const int lane = tid & 63;
    const int wid = tid >> 6;
    const int g = lane >> 4, c = lane & 15;
    const int bh = blockIdx.y;
    const int base = bh * 65536;  // 1024*64
    const int b = bh >> 4, h = bh & 15;

    const int r0 = tid >> 3, c0 = (tid & 7) << 3;
    const int r1 = 64 + r0;
    const int vt0 = (tid >> 4) * 4;   // 0..124
    const int vd0 = (tid & 15) * 4;   // 0..60

    const f32x4 fz = {0.f, 0.f, 0.f, 0.f};

    bf16x8 kreg0, kreg1;
    short4v vreg0, vreg1, vreg2, vreg3;

#pragma unroll 1
    for (int ph = 0; ph < 2; ++ph) {
        const int qt = ph ? (7 - blockIdx.x) : blockIdx.x;
        const int q0 = qt * 128;
        const int nkt = qt + 1;

        const int qrow = q0 + wid * 16 + c;
        bf16x8 qf0 = *(const bf16x8*)(qp + base + qrow * 64 + g * 8);
        bf16x8 qf1 = *(const bf16x8*)(qp + base + qrow * 64 + 32 + g * 8);

        f32x4 accO[4];
#pragma unroll
        for (int n = 0; n < 4; ++n) accO[n] = fz;
        float mrow[4], lsum[4];
#pragma unroll
        for (int i = 0; i < 4; ++i) { mrow[i] = -1e30f; lsum[i] = 0.f; }

        kreg0 = *(const bf16x8*)(kp + base + r0 * 64 + c0);
        kreg1 = *(const bf16x8*)(kp + base + r1 * 64 + c0);
        vreg0 = *(const short4v*)(vp + base + (vt0 + 0) * 64 + vd0);
        vreg1 = *(const short4v*)(vp + base + (vt0 + 1) * 64 + vd0);
        vreg2 = *(const short4v*)(vp + base + (vt0 + 2) * 64 + vd0);
        vreg3 = *(const short4v*)(vp + base + (vt0 + 3) * 64 + vd0);

        for (int kt = 0; kt < nkt; ++kt) {
            __syncthreads();
            *(bf16x8*)((char*)Ks + r0 * 128 + ((c0 * 2) ^ ((r0 & 7) << 4))) = kreg0;
            *(bf16x8*)((char*)Ks + r1 * 128 + ((c0 * 2) ^ ((r1 & 7) << 4))) = kreg1;
#pragma unroll
            for (int i = 0; i < 4; ++i) {
                short4v w; w[0] = vreg0[i]; w[1] = vreg1[i]; w[2] = vreg2[i]; w[3] = vreg3[i];
                int d = vd0 + i;
                int swz = ((d & 7) ^ (d >> 3)) << 4;
                *(short4v*)((char*)Vt + d * 256 + ((vt0 * 2) ^ swz)) = w;
            }
            if (kt + 1 < nkt) {
                const short* kp2 = kp + base + (kt + 1) * 8192;
                const short* vp2 = vp + base + (kt + 1) * 8192;
                kreg0 = *(const bf16x8*)(kp2 + r0 * 64 + c0);
                kreg1 = *(const bf16x8*)(kp2 + r1 * 64 + c0);
                vreg0 = *(const short4v*)(vp2 + (vt0 + 0) * 64 + vd0);
                vreg1 = *(const short4v*)(vp2 + (vt0 + 1) * 64 + vd0);
                vreg2 = *(const short4v*)(vp2 + (vt0 + 2) * 64 + vd0);
                vreg3 = *(const short4v*)(vp2 + (vt0 + 3) * 64 + vd0);
            }
            __syncthreads();

            const bool diag = (kt == nkt - 1);
            const int nlim = diag ? (wid + 1) : 8;

            f32x4 s[8];
            __builtin_amdgcn_s_setprio(1);
#pragma unroll
            for (int n = 0; n < 8; ++n) {
                s[n] = fz;
                if (n < nlim) {
                    int row = n * 16 + c;
                    int swz = (row & 7) << 4;
                    bf16x8 kf0 = *(const bf16x8*)((const char*)Ks + row * 128 + ((g * 16) ^ swz));
                    bf16x8 kf1 = *(const bf16x8*)((const char*)Ks + row * 128 + ((64 + g * 16) ^ swz));
                    s[n] = __builtin_amdgcn_mfma_f32_16x16x32_bf16(qf0, kf0, s[n], 0, 0, 0);
                    s[n] = __builtin_amdgcn_mfma_f32_16x16x32_bf16(qf1, kf1, s[n], 0, 0, 0);
                }
            }
            __builtin_amdgcn_s_setprio(0);

            const int qg0 = q0 + wid * 16 + g * 4;
            float pm[4];
#pragma unroll
            for (int i = 0; i < 4; ++i) pm[i] = -1e30f;
            if (diag) {
#pragma unroll
                for (int n = 0; n < 8; ++n) {
                    int kg = kt * 128 + n * 16 + c;
#pragma unroll
                    for (int i = 0; i < 4; ++i) {
                        float vv = s[n][i] * SCALE;
                        vv = (kg <= qg0 + i) ? vv : -1e30f;
                        s[n][i] = vv;
                        pm[i] = fmaxf(pm[i], vv);
                    }
                }
            } else {
#pragma unroll
                for (int n = 0; n < 8; ++n)
#pragma unroll
                    for (int i = 0; i < 4; ++i) {
                        float vv = s[n][i] * SCALE;
                        s[n][i] = vv;
                        pm[i] = fmaxf(pm[i], vv);
                    }
            }
#pragma unroll
            for (int off = 1; off < 16; off <<= 1)
#pragma unroll
                for (int i = 0; i < 4; ++i)
                    pm[i] = fmaxf(pm[i], __shfl_xor(pm[i], off));

            // online softmax update with defer-max (T13); lsum deferred (no per-tile reduce)
            int need = 0;
#pragma unroll
            for (int i = 0; i < 4; ++i) need |= (pm[i] > mrow[i] + 8.f) ? 1 : 0;
            if (__any(need)) {
#pragma unroll
                for (int i = 0; i < 4; ++i) {
                    float mnew = fmaxf(mrow[i], pm[i]);
                    float corr = exp2f(mrow[i] - mnew);
                    mrow[i] = mnew;
                    lsum[i] *= corr;
#pragma unroll
                    for (int n = 0; n < 4; ++n) accO[n][i] *= corr;
                }
            }
#pragma unroll
            for (int n = 0; n < 8; ++n)
#pragma unroll
                for (int i = 0; i < 4; ++i) {
                    float pv = exp2f(s[n][i] - mrow[i]);
                    s[n][i] = pv;
                    lsum[i] += pv;
                }

            // ---- PV in two 64-key halves through the small per-wave Ps buffer ----
#pragma unroll
            for (int hf = 0; hf < 2; ++hf) {
                // WAR guard: prior PV reads of Ps must have completed
                asm volatile("s_waitcnt lgkmcnt(0)" ::: "memory");
                __builtin_amdgcn_sched_barrier(0);
#pragma unroll
                for (int n4 = 0; n4 < 4; ++n4) {
                    int tl = n4 * 16 + c;
#pragma unroll
                    for (int i = 0; i < 4; ++i) {
                        int q = g * 4 + i;
                        *(short*)((char*)&Ps[wid][0] + q * 128 + ((tl * 2) ^ ((q & 7) << 4))) =
                            f2bf(s[hf * 4 + n4][i]);
                    }
                }
                asm volatile("s_waitcnt lgkmcnt(0)" ::: "memory");
                __builtin_amdgcn_sched_barrier(0);
#pragma unroll
                for (int ksl = 0; ksl < 2; ++ksl) {
                    const int ks = hf * 2 + ksl;
                    bf16x8 paf = *(const bf16x8*)((const char*)&Ps[wid][0] +
                                                  c * 128 + ((ksl * 64 + g * 16) ^ ((c & 7) << 4)));
                    __builtin_amdgcn_s_setprio(1);
#pragma unroll
                    for (int n = 0; n < 4; ++n) {
                        int d = n * 16 + c;
                        int swz = ((d & 7) ^ (d >> 3)) << 4;
                        bf16x8 vf = *(const bf16x8*)((const char*)Vt + d * 256 + ((ks * 64 + g * 16) ^ swz));
                        accO[n] = __builtin_amdgcn_mfma_f32_16x16x32_bf16(paf, vf, accO[n], 0, 0, 0);
                    }
                    __builtin_amdgcn_s_setprio(0);
                }
            }
        }

        // epilogue: reduce deferred row-sums, normalize, store
        float lrow[4];
#pragma unroll
        for (int i = 0; i < 4; ++i) lrow[i] = lsum[i];
#pragma unroll
        for (int off = 1; off < 16; off <<= 1)
#pragma unroll
            for (int i = 0; i < 4; ++i)
                lrow[i] += __shfl_xor(lrow[i], off);
        float inv[4];
#pragma unroll
        for (int i = 0; i < 4; ++i) inv[i] = __builtin_amdgcn_rcpf(lrow[i]);
#pragma unroll
        for (int n = 0; n < 4; ++n)
#pragma unroll
            for (int i = 0; i < 4; ++i) {
                int t = q0 + wid * 16 + g * 4 + i;
                float o = accO[n][i] * inv[i];
                ao[(b * 1024 + t) * 1024 + h * 64 + n * 16 + c] = f2bf(o);
            }
    }
}

extern "C" void kernel_launch(void* const* d_in, const int* in_sizes, int n_in,
                              void* d_out, int out_size, void* d_ws, size_t ws_size,
                              hipStream_t stream) {
    const float* x  = (const float*)d_in[0];
    const float* Wq = (const float*)d_in[1];
    const float* Wk = (const float*)d_in[2];
    const float* Wv = (const float*)d_in[3];
    const float* Wo = (const float*)d_in[4];
    const float* bo = (const float*)d_in[5];
    const float* W1 = (const float*)d_in[6];
    const float* b1 = (const float*)d_in[7];

    char* ws = (char*)d_ws;
    short* xb    = (short*)(ws + 0);          // 16.78 MB  [8192][1024] bf16
    short* wallT = (short*)(ws + 16777216);   // 10.49 MB  5x [1024][1024] bf16 (Wq,Wk,Wv,Wo,W1)^T
    short* qb    = (short*)(ws + 27262976);   // 3 x 16.78 MB: q,k,v [B*H][T][64] bf16
    short* kb    = qb + 8388608;
    short* vb    = qb + 16777216;
    short* ao    = xb;                        // reuse: attention out [8192][1024] bf16
    short* o2    = qb;                        // reuse: Wo out [8192][1024] bf16
    short* wqkvT = wallT;                     // Wq^T|Wk^T|Wv^T contiguous
    short* woT   = wallT + 3145728;
    short* w1T   = wallT + 4194304;

    cvt_x_kernel<<<4096, 256, 0, stream>>>(x, xb);
    wtrans5_kernel<<<dim3(16, 16, 5), 256, 0, stream>>>(Wq, Wk, Wv, Wo, W1, wallT);

    gemm_bt<0><<<dim3(64, 24), 256, 0, stream>>>(xb, wqkvT, nullptr, (void*)qb);
    attn_kernel<<<dim3(4, 128), 512, 0, stream>>>(qb, kb, vb, ao);
    gemm_bt<1><<<dim3(64, 8), 256, 0, stream>>>(ao, woT, bo, (void*)o2);
    gemm_bt<2><<<dim3(64, 8), 256, 0, stream>>>(o2, w1T, b1, d_out);
}